// Round 3
// baseline (383.112 us; speedup 1.0000x reference)
//
#include <hip/hip_runtime.h>
#include <cstdint>
#include <cstddef>

// ---------------------------------------------------------------------------
// NodeDegreeExpansionBlock: fused MFMA implementation for gfx950.
// Key idea: every big contraction is  (rank-1-synthesized A) @ (dense B),
// A[n, u*64+v] = p[n,u]*q[n,v].  A-frags built in registers (pk f16 mul),
// B pre-converted to fp16 in MFMA-fragment order -> direct global b128 loads,
// no LDS, no barriers in the K loop.
// R3: kbig reverted to the R0 inner loop (proven codegen) + TLP/locality fix:
//  - 704 uniform-duration blocks (z0 K-split x2 = 512 short, z1 unsplit = 192
//    long) -> all blocks resident at t=0 (<= 3 blocks/CU capacity).
//  - __launch_bounds__(256,3) so registers fit 3 blocks/CU (12 waves/CU TLP
//    to hide the ~500cy L3 latency on B-streams).
//  - bid&7 = XCD bin; each bin's blocks read <= 4MB of distinct B streams
//    (L2-resident per XCD); duration-balanced bins (24 long + 64 short).
//  - z0's 4 extra K-partials aliased into Y0+Y1 / O0+O1 (dead until after
//    kreduce) -> no workspace growth.
//  - kgemm_small MODE0+MODE1 fused into one launch. 7 dispatches total.
// ---------------------------------------------------------------------------

typedef _Float16 half8 __attribute__((ext_vector_type(8)));
typedef _Float16 half4v __attribute__((ext_vector_type(4)));
typedef float f32x4 __attribute__((ext_vector_type(4)));

static constexpr float INV_H  = 0.08838834764831845f;   // 1/sqrt(128)
static constexpr float INV_U  = 0.125f;                 // 1/sqrt(64)
static constexpr float INV_TP = 0.0078125f;             // 1/sqrt(2*128*64)
static constexpr float INV_SC = 0.02795084971874737f;   // 1/sqrt(128*10)
static constexpr float RSQRT3 = 0.5773502691896258f;
static constexpr float LN_EPS = 1e-5f;

// ---- workspace layout (bytes) ----
static constexpr size_t OFF_BZ0 = 0;                     // fp16 frag-ordered [nt(2)][u(256)] 16KB tiles
static constexpr size_t OFF_BZ1 = OFF_BZ0 + 8388608;     // fp16 frag-ordered [u(256)] 16KB tiles
static constexpr size_t OFF_WH0 = OFF_BZ1 + 4194304;
static constexpr size_t OFF_WH1 = OFF_WH0 + 32768;
static constexpr size_t OFF_WU0 = OFF_WH1 + 32768;
static constexpr size_t OFF_WU1 = OFF_WU0 + 8192;
static constexpr size_t OFF_WP0 = OFF_WU1 + 8192;
static constexpr size_t OFF_WP1 = OFF_WP0 + 32768;
static constexpr size_t OFF_WS0 = OFF_WP1 + 32768;
static constexpr size_t OFF_WS1 = OFF_WS0 + 32768;
static constexpr size_t OFF_H0F = OFF_WS1 + 32768;       // f16 (4096,128)
static constexpr size_t OFF_H1F = OFF_H0F + 1048576;     // f16 3 planes (4096,128)
static constexpr size_t OFF_U0F = OFF_H1F + 3145728;     // f16 (4096,64)
static constexpr size_t OFF_U1F = OFF_U0F + 524288;      // f16 3 planes (4096,64)
static constexpr size_t OFF_HP0 = OFF_U1F + 1572864;     // f16 (4096,128)
static constexpr size_t OFF_HP1 = OFF_HP0 + 1048576;     // f16 3 planes
static constexpr size_t OFF_UP0 = OFF_HP1 + 3145728;     // f16 (4096,64)
static constexpr size_t OFF_UP1 = OFF_UP0 + 524288;      // f16 3 planes
static constexpr size_t OFF_SF  = OFF_UP1 + 1572864;     // f16 (4096,128) silu(z0a)
static constexpr size_t OFF_VF  = OFF_SF + 1048576;      // f16 3 planes v = z1*g
static constexpr size_t OFF_PZ0 = OFF_VF + 3145728;      // f32 4 x (4096,256) z0 partials (ks=0)
static constexpr size_t OFF_PZ1 = OFF_PZ0 + 16777216;    // f32 2 x (12288,128) z1 partials
static constexpr size_t OFF_Y0  = OFF_PZ1 + 12582912;    // f32 (4096,128)  [pre-kreduce: z0 ks=1 partials kj0,1]
static constexpr size_t OFF_Y1  = OFF_Y0 + 2097152;      // f32 3 planes (4096,128)
static constexpr size_t OFF_O0  = OFF_Y1 + 6291456;      // f32 (4096,128)  [pre-kreduce: z0 ks=1 partials kj2,3]
static constexpr size_t OFF_O1  = OFF_O0 + 2097152;      // f32 3 planes
static constexpr size_t OFF_SP  = OFF_O1 + 6291456;      // int (4096)
static constexpr size_t OFF_ST  = OFF_SP + 16384;        // f32 stats: S0,SS0,SS1,CNT (64 each)
static constexpr size_t WS_NEED = OFF_ST + 2048;

// ---------------------------------------------------------------------------
// kconv: all weight conversions (fp32 -> fp16, fragment-ordered), input
// converts/deinterleaves, species argmax, stats-buffer zeroing.
// Frag-ordered big-B tile (16KB per (nt,u)): chunk ch=f*2+c, lane, j holds
// B[w=f*16+(lane&15)][k_in_u = c*32+(lane>>4)*8+j].
// ---------------------------------------------------------------------------
__global__ __launch_bounds__(256) void kconv(
    const float* __restrict__ nfh, const float* __restrict__ nfu,
    const float* __restrict__ onehot,
    const float* __restrict__ Wt00, const float* __restrict__ Wt11,
    const float* __restrict__ Wt01, const float* __restrict__ Wt10,
    const float* __restrict__ Wh0, const float* __restrict__ Wh1,
    const float* __restrict__ Wu0, const float* __restrict__ Wu1,
    const float* __restrict__ Wp0, const float* __restrict__ Wp1,
    const float* __restrict__ Ws0, const float* __restrict__ Ws1,
    char* __restrict__ ws)
{
  const int bid = blockIdx.x, t = threadIdx.x;
  if (bid < 768) {
    _Float16* dst;
    int u, nt = 0;
    const bool isz0 = bid < 512;
    if (isz0) { nt = bid >> 8; u = bid & 255; dst = (_Float16*)(ws + OFF_BZ0) + ((size_t)nt*256 + (size_t)u)*8192; }
    else      { u = bid - 512;               dst = (_Float16*)(ws + OFF_BZ1) + (size_t)u*8192; }
    for (int it = 0; it < 4; ++it) {
      int chunk = it*256 + t;               // 0..1023 16B-chunks
      int lane = chunk & 63, ch = chunk >> 6;
      int f = ch >> 1, c = ch & 1;
      int w = f*16 + (lane & 15);
      int v0 = c*32 + (lane >> 4)*8;
      half8 o;
      #pragma unroll
      for (int j = 0; j < 8; ++j) {
        float val;
        if (isz0) {
          if (u < 128) val = Wt00[(size_t)((u*64 + v0 + j)*256) + nt*128 + w];
          else         val = Wt11[(size_t)(((u-128)*64 + v0 + j)*256) + nt*128 + w] * RSQRT3;
        } else {
          if (u < 128) val = Wt01[(size_t)((u*64 + v0 + j)*128) + w];
          else         val = Wt10[(size_t)(((u-128)*64 + v0 + j)*128) + w];
        }
        o[j] = (_Float16)val;
      }
      *(half8*)(dst + (size_t)chunk*8) = o;
    }
  } else if (bid < 776) {
    // small weights -> frag order: chunk q = (c*(N/16)+f)*64+lane,
    // value = W[k=c*32+(lane>>4)*8+j][n=f*16+(lane&15)]
    int mat = bid - 768;
    const float* src; size_t doff; int K, N;
    switch (mat) {
      case 0: src = Wh0; doff = OFF_WH0; K = 128; N = 128; break;
      case 1: src = Wh1; doff = OFF_WH1; K = 128; N = 128; break;
      case 2: src = Wu0; doff = OFF_WU0; K = 64;  N = 64;  break;
      case 3: src = Wu1; doff = OFF_WU1; K = 64;  N = 64;  break;
      case 4: src = Wp0; doff = OFF_WP0; K = 128; N = 128; break;
      case 5: src = Wp1; doff = OFF_WP1; K = 128; N = 128; break;
      case 6: src = Ws0; doff = OFF_WS0; K = 128; N = 128; break;
      default: src = Ws1; doff = OFF_WS1; K = 128; N = 128; break;
    }
    _Float16* d = (_Float16*)(ws + doff);
    const int nfr = N >> 4;
    const int chunks = (K*N) >> 3;
    for (int qd = t; qd < chunks; qd += 256) {
      int lane = qd & 63, cf = qd >> 6;
      int f = cf % nfr, c = cf / nfr;
      int col = f*16 + (lane & 15);
      int k0 = c*32 + (lane >> 4)*8;
      half8 o;
      #pragma unroll
      for (int j = 0; j < 8; ++j) o[j] = (_Float16)src[(size_t)(k0 + j)*N + col];
      *(half8*)(d + (size_t)qd*8) = o;
    }
  } else if (bid < 1544) {
    // input fp32 -> fp16 converts / i-plane deinterleaves
    const int stride = 768*256;
    const int base = (bid - 776)*256 + t;
    _Float16* h0f = (_Float16*)(ws + OFF_H0F);
    _Float16* h1f = (_Float16*)(ws + OFF_H1F);
    _Float16* u0f = (_Float16*)(ws + OFF_U0F);
    _Float16* u1f = (_Float16*)(ws + OFF_U1F);
    for (int id = base; id < 524288; id += stride)
      h0f[id] = (_Float16)nfh[(size_t)(id >> 7)*512 + (id & 127)];
    for (int id = base; id < 1572864; id += stride) {
      int i = id >> 19, r = id & 524287, n = r >> 7, u = r & 127;
      h1f[id] = (_Float16)nfh[(size_t)n*512 + 128 + u*3 + i];
    }
    for (int id = base; id < 262144; id += stride)
      u0f[id] = (_Float16)nfu[(size_t)(id >> 6)*256 + (id & 63)];
    for (int id = base; id < 786432; id += stride) {
      int i = id >> 18, r = id & 262143, n = r >> 6, v = r & 63;
      u1f[id] = (_Float16)nfu[(size_t)n*256 + 64 + v*3 + i];
    }
  } else {
    int node = (bid - 1544)*256 + t;
    const float* row = onehot + (size_t)node*10;
    int best = 0; float bv = row[0];
    #pragma unroll
    for (int s = 1; s < 10; ++s) { float v = row[s]; if (v > bv) { bv = v; best = s; } }
    ((int*)(ws + OFF_SP))[node] = best;
    if (bid == 1544) {           // zero group-stats accumulators (replaces memset)
      float* stz = (float*)(ws + OFF_ST);
      stz[t] = 0.f; stz[t + 256] = 0.f;
    }
  }
}

// ---------------------------------------------------------------------------
// gemm_small_body: C[n, m] = scale * sum_k A[n,k] * W[k,m] (+bias), MFMA
// 16x16x32. 128 nodes per block, 4 waves x 32 rows. A: f16 (n,K) rows.
// W: frag-ordered. MODE 0: h-family prep (f16 out); MODE 1: u-family prep
// (f16 out); MODE 2: tail GEMMs (f32 out, optional bias).
// ---------------------------------------------------------------------------
template<int KK, int NO, int MODE>
__device__ __forceinline__ void gemm_small_body(char* __restrict__ ws,
    const float* __restrict__ bp0, const float* __restrict__ bs0,
    int bid, int t)
{
  constexpr int NT = NO / 16;
  const int lane = t & 63, wid = t >> 6;
  const int quad = lane >> 4, l15 = lane & 15;
  const int job = bid >> 5, n0 = (bid & 31) << 7;

  const _Float16 *A, *W;
  _Float16* oh = nullptr; float* of = nullptr;
  const float* bias = nullptr;
  float scale;
  if constexpr (MODE == 0) {
    scale = INV_H;
    if (job == 0) { A = (const _Float16*)(ws + OFF_H0F); W = (const _Float16*)(ws + OFF_WH0); oh = (_Float16*)(ws + OFF_HP0); }
    else {
      A = (const _Float16*)(ws + OFF_H1F) + (size_t)(job-1)*524288;
      W = (const _Float16*)(ws + OFF_WH1);
      oh = (_Float16*)(ws + OFF_HP1) + (size_t)(job-1)*524288;
    }
  } else if constexpr (MODE == 1) {
    scale = INV_U;
    if (job == 0) { A = (const _Float16*)(ws + OFF_U0F); W = (const _Float16*)(ws + OFF_WU0); oh = (_Float16*)(ws + OFF_UP0); }
    else {
      A = (const _Float16*)(ws + OFF_U1F) + (size_t)(job-1)*262144;
      W = (const _Float16*)(ws + OFF_WU1);
      oh = (_Float16*)(ws + OFF_UP1) + (size_t)(job-1)*262144;
    }
  } else {
    scale = INV_H;
    switch (job) {
      case 0: A = (const _Float16*)(ws + OFF_SF);  W = (const _Float16*)(ws + OFF_WP0); of = (float*)(ws + OFF_Y0); bias = bp0; break;
      case 1: A = (const _Float16*)(ws + OFF_H0F); W = (const _Float16*)(ws + OFF_WS0); of = (float*)(ws + OFF_O0); bias = bs0; break;
      case 2: case 3: case 4:
        A = (const _Float16*)(ws + OFF_VF) + (size_t)(job-2)*524288;
        W = (const _Float16*)(ws + OFF_WP1);
        of = (float*)(ws + OFF_Y1) + (size_t)(job-2)*524288; break;
      default:
        A = (const _Float16*)(ws + OFF_H1F) + (size_t)(job-5)*524288;
        W = (const _Float16*)(ws + OFF_WS1);
        of = (float*)(ws + OFF_O1) + (size_t)(job-5)*524288; break;
    }
  }

  f32x4 acc[2][NT];
  const f32x4 zz = {0.f, 0.f, 0.f, 0.f};
  #pragma unroll
  for (int mf = 0; mf < 2; ++mf)
    #pragma unroll
    for (int nf = 0; nf < NT; ++nf) acc[mf][nf] = zz;

  #pragma unroll
  for (int kc = 0; kc < KK/32; ++kc) {
    half8 a[2];
    #pragma unroll
    for (int mf = 0; mf < 2; ++mf)
      a[mf] = *(const half8*)(A + (size_t)(n0 + wid*32 + mf*16 + l15)*KK + kc*32 + quad*8);
    #pragma unroll
    for (int nf = 0; nf < NT; ++nf) {
      half8 b = *(const half8*)(W + (size_t)(kc*NT + nf)*512 + lane*8);
      #pragma unroll
      for (int mf = 0; mf < 2; ++mf)
        acc[mf][nf] = __builtin_amdgcn_mfma_f32_16x16x32_f16(a[mf], b, acc[mf][nf], 0, 0, 0);
    }
  }

  #pragma unroll
  for (int mf = 0; mf < 2; ++mf)
    #pragma unroll
    for (int nf = 0; nf < NT; ++nf) {
      int col = nf*16 + l15;
      float bv = bias ? bias[col] : 0.f;
      #pragma unroll
      for (int r = 0; r < 4; ++r) {
        int row = n0 + wid*32 + mf*16 + quad*4 + r;
        float v = acc[mf][nf][r] * scale + bv;
        if constexpr (MODE < 2) oh[(size_t)row*NO + col] = (_Float16)v;
        else                    of[(size_t)row*NO + col] = v;
      }
    }
}

// kprep: MODE0 (h-family, 128 blocks) + MODE1 (u-family, 128 blocks) fused.
__global__ __launch_bounds__(256) void kprep(char* __restrict__ ws)
{
  if (blockIdx.x < 128) gemm_small_body<128,128,0>(ws, nullptr, nullptr, blockIdx.x, threadIdx.x);
  else                  gemm_small_body<64, 64, 1>(ws, nullptr, nullptr, blockIdx.x - 128, threadIdx.x);
}

// ktail: MODE2 (8 tail GEMM jobs, 256 blocks).
__global__ __launch_bounds__(256) void ktail(char* __restrict__ ws,
    const float* __restrict__ bp0, const float* __restrict__ bs0)
{
  gemm_small_body<128,128,2>(ws, bp0, bs0, blockIdx.x, threadIdx.x);
}

// ---------------------------------------------------------------------------
// bigloop: one 128x128 output tile over nu4*4 u-steps (K = nu4*256).
// A[n, u*64+v] = p[n,u]*q[n,v] synthesized in regs; B read directly from
// frag-ordered fp16 global (L2-resident per XCD). R0-proven inner loop.
// 4 waves: wy row-half, wx col-half; per wave mf=4 x nf=4 16x16 frags.
// ---------------------------------------------------------------------------
__device__ __forceinline__ void bigloop(
    const _Float16* __restrict__ p, const _Float16* __restrict__ q,
    const _Float16* __restrict__ B0,
    float* __restrict__ out, size_t obase, int opitch,
    int node0, int ustart4, int nu4, int t)
{
  const int lane = t & 63, wid = t >> 6;
  const int wy = wid >> 1, wx = wid & 1;
  const int quad = lane >> 4, l15 = lane & 15;

  // q fragments: fixed for the whole K loop (A[m][k]=p[m,u]*q[m,v], v=k&63)
  half8 qf[4][2];
  #pragma unroll
  for (int mf = 0; mf < 4; ++mf)
    #pragma unroll
    for (int c = 0; c < 2; ++c)
      qf[mf][c] = *(const half8*)(q + (size_t)(node0 + wy*64 + mf*16 + l15)*64 + c*32 + quad*8);

  f32x4 acc[4][4];
  const f32x4 zz = {0.f, 0.f, 0.f, 0.f};
  #pragma unroll
  for (int mf = 0; mf < 4; ++mf)
    #pragma unroll
    for (int nf = 0; nf < 4; ++nf) acc[mf][nf] = zz;

  const _Float16* prow = p + (size_t)(node0 + wy*64 + l15)*128 + ustart4*4;
  const _Float16* Bw = B0 + (size_t)ustart4*32768 + (size_t)wx*4096 + (size_t)lane*8;

  for (int u4 = 0; u4 < nu4; ++u4) {
    half4v pw[4];
    #pragma unroll
    for (int mf = 0; mf < 4; ++mf)
      pw[mf] = *(const half4v*)(prow + (size_t)mf*2048 + u4*4);
    #pragma unroll
    for (int uu = 0; uu < 4; ++uu) {
      const _Float16* Bu = Bw + (size_t)(u4*4 + uu)*8192;
      half8 bf[2][4];
      #pragma unroll
      for (int c = 0; c < 2; ++c)
        #pragma unroll
        for (int nf = 0; nf < 4; ++nf)
          bf[c][nf] = *(const half8*)(Bu + (size_t)((nf*2 + c)*512));
      #pragma unroll
      for (int mf = 0; mf < 4; ++mf) {
        const _Float16 ps = pw[mf][uu];
        const half8 pv = {ps, ps, ps, ps, ps, ps, ps, ps};
        #pragma unroll
        for (int c = 0; c < 2; ++c) {
          half8 a = qf[mf][c] * pv;
          #pragma unroll
          for (int nf = 0; nf < 4; ++nf)
            acc[mf][nf] = __builtin_amdgcn_mfma_f32_16x16x32_f16(a, bf[c][nf], acc[mf][nf], 0, 0, 0);
        }
      }
    }
  }

  #pragma unroll
  for (int mf = 0; mf < 4; ++mf)
    #pragma unroll
    for (int nf = 0; nf < 4; ++nf) {
      int col = wx*64 + nf*16 + l15;
      #pragma unroll
      for (int r = 0; r < 4; ++r) {
        int row = wy*64 + mf*16 + quad*4 + r;
        out[obase + (size_t)row*opitch + col] = acc[mf][nf][r];
      }
    }
}

// ---------------------------------------------------------------------------
// kbig: 704 blocks, XCD-binned (bid&7) with duration-balanced bins:
// per bin 24 z1 blocks (K=8192, "long") + 64 z0 blocks (K=4096, "short").
// Streams per bin: one z0_00 (nt,ks) 1MB + one z0_11 (nt,ks) 1MB + half of
// one z1 (kj) 2MB  => <=4MB distinct B per XCD -> L2-resident.
// z0 partials: (kj,ks): ks0 -> PZ0[kj]; ks1 kj0,1 -> Y0+Y1 region;
//              ks1 kj2,3 -> O0+O1 region (dead until after kreduce).
// z1 partials: PZ1[kj] (2 x 6MB).
// ---------------------------------------------------------------------------
__global__ __launch_bounds__(256, 3) void kbig(char* __restrict__ ws)
{
  const int bid = blockIdx.x, t = threadIdx.x;
  const int xcd = bid & 7, j = bid >> 3;          // j in 0..87

  const _Float16* hp0 = (const _Float16*)(ws + OFF_HP0);
  const _Float16* hp1 = (const _Float16*)(ws + OFF_HP1);
  const _Float16* up0 = (const _Float16*)(ws + OFF_UP0);
  const _Float16* up1 = (const _Float16*)(ws + OFF_UP1);
  const _Float16* BZ0 = (const _Float16*)(ws + OFF_BZ0);
  const _Float16* BZ1 = (const _Float16*)(ws + OFF_BZ1);

  if (j < 24) {
    // ---- z1 block: kj = xcd>>2, member g = (xcd&3)*24 + j in 0..95 ----
    const int kj = xcd >> 2;
    const int g = (xcd & 3)*24 + j;
    const int i = g >> 5, mt = g & 31;
    const int node0 = mt << 7;
    const _Float16 *p, *q;
    if (kj == 0) { p = hp0; q = up1 + (size_t)i*262144; }
    else         { p = hp1 + (size_t)i*524288; q = up0; }
    const _Float16* B0 = BZ1 + (kj ? (size_t)1048576 : (size_t)0);
    float* out = (float*)(ws + OFF_PZ1) + (size_t)kj*1572864;
    bigloop(p, q, B0, out, (size_t)(i*32 + mt)*16384, 128, node0, 0, 32, t);
  } else {
    // ---- z0 block: stream pair s = xcd&3 -> (nt, ks) ----
    const int s = xcd & 3, nt = s >> 1, ks = s & 1;
    const int j2 = j - 24;                        // 0..63
    int kj, mt;
    if (j2 < 48) {   // z0_11: g = (xcd>>2)*48 + j2 in 0..95 -> (i, mt)
      const int g = (xcd >> 2)*48 + j2;
      kj = 1 + (g >> 5); mt = g & 31;
    } else {         // z0_00
      kj = 0; mt = (xcd >> 2)*16 + (j2 - 48);     // 0..31
    }
    const int node0 = mt << 7;
    const _Float16 *p, *q;
    if (kj == 0) { p = hp0; q = up0; }
    else { p = hp1 + (size_t)(kj-1)*524288; q = up1 + (size_t)(kj-1)*262144; }
    const _Float16* B0 = BZ0 + (size_t)nt*2097152 + (kj ? (size_t)1048576 : (size_t)0);
    float* out;
    if (ks == 0)      out = (float*)(ws + OFF_PZ0) + (size_t)kj*1048576;
    else if (kj < 2)  out = (float*)(ws + OFF_Y0)  + (size_t)kj*1048576;
    else              out = (float*)(ws + OFF_O0)  + (size_t)(kj-2)*1048576;
    bigloop(p, q, B0, out, (size_t)node0*256 + (size_t)nt*128, 256, node0, ks*16, 16, t);
  }
}

// ---------------------------------------------------------------------------
// kreduce: sum K-partials, apply inv_tp, silu/sigmoid gates, emit s,v (fp16).
// z0 has 8 partials (4 kj x 2 ks); z1 has 2 (kj).
// ---------------------------------------------------------------------------
__global__ __launch_bounds__(256) void kreduce(char* __restrict__ ws)
{
  const int id = blockIdx.x*256 + threadIdx.x;   // < 4096*128
  const int n = id >> 7, w = id & 127;
  const float* pz0 = (const float*)(ws + OFF_PZ0);
  const float* pe0 = (const float*)(ws + OFF_Y0);
  const float* pe1 = (const float*)(ws + OFF_O0);
  const float* pz1 = (const float*)(ws + OFF_PZ1);
  _Float16* sf = (_Float16*)(ws + OFF_SF);
  _Float16* vf = (_Float16*)(ws + OFF_VF);
  const size_t b = (size_t)n*256;
  float zs = (pz0[b + w] + pz0[1048576 + b + w] + pz0[2097152 + b + w] + pz0[3145728 + b + w]
            + pe0[b + w] + pe0[1048576 + b + w] + pe1[b + w] + pe1[1048576 + b + w]) * INV_TP;
  float zg = (pz0[b + 128 + w] + pz0[1048576 + b + 128 + w] + pz0[2097152 + b + 128 + w] + pz0[3145728 + b + 128 + w]
            + pe0[b + 128 + w] + pe0[1048576 + b + 128 + w] + pe1[b + 128 + w] + pe1[1048576 + b + 128 + w]) * INV_TP;
  float s = zs / (1.f + __expf(-zs));
  float g = 1.f / (1.f + __expf(-zg));
  sf[id] = (_Float16)s;
  #pragma unroll
  for (int i = 0; i < 3; ++i) {
    size_t r = ((size_t)i*4096 + (size_t)n)*128 + w;
    float z1v = (pz1[r] + pz1[1572864 + r]) * INV_TP;
    vf[(size_t)i*524288 + (size_t)n*128 + w] = (_Float16)(z1v * g);
  }
}

// ---------------------------------------------------------------------------
// kscstats: species-gathered skip terms, y0/y1 += inv_sc * h @ Wsc[:,sp,:],
// fused with the per-group stat accumulation (y values kept in registers).
// 2 nodes per block (waves 0,1 -> node A; waves 2,3 -> node B).
// ---------------------------------------------------------------------------
__global__ __launch_bounds__(256) void kscstats(char* __restrict__ ws,
    const float* __restrict__ nfh,
    const float* __restrict__ Wsc0, const float* __restrict__ Wsc1,
    const int* __restrict__ batch)
{
  const int t = threadIdx.x;
  const int node = blockIdx.x*2 + (t >> 7);
  const int w = t & 127;
  const int sp = ((const int*)(ws + OFF_SP))[node];
  const float* h = nfh + (size_t)node*512;
  float a0 = 0.f, a10 = 0.f, a11 = 0.f, a12 = 0.f;
  for (int u = 0; u < 128; ++u) {
    const size_t wi = (size_t)(u*10 + sp)*128 + w;
    float w0 = Wsc0[wi];
    float w1 = Wsc1[wi];
    a0 += h[u] * w0;
    a10 += h[128 + u*3 + 0] * w1;
    a11 += h[128 + u*3 + 1] * w1;
    a12 += h[128 + u*3 + 2] * w1;
  }
  float* y0 = (float*)(ws + OFF_Y0);
  float* y1 = (float*)(ws + OFF_Y1);
  const size_t i0 = (size_t)node*128 + w;
  float y0n  = y0[i0]           + INV_SC * a0;
  float y1n0 = y1[i0]           + INV_SC * a10;
  float y1n1 = y1[524288 + i0]  + INV_SC * a11;
  float y1n2 = y1[1048576 + i0] + INV_SC * a12;
  y0[i0] = y0n;
  y1[i0] = y1n0;
  y1[524288 + i0]  = y1n1;
  y1[1048576 + i0] = y1n2;

  float s0 = y0n, ss0 = y0n*y0n, ss1 = y1n0*y1n0 + y1n1*y1n1 + y1n2*y1n2;
  #pragma unroll
  for (int m = 1; m < 64; m <<= 1) {
    s0  += __shfl_xor(s0, m, 64);
    ss0 += __shfl_xor(ss0, m, 64);
    ss1 += __shfl_xor(ss1, m, 64);
  }
  __shared__ float red[4][3];
  if ((t & 63) == 0) {
    red[t >> 6][0] = s0; red[t >> 6][1] = ss0; red[t >> 6][2] = ss1;
  }
  __syncthreads();
  if ((t & 127) == 0) {
    const int wv = t >> 6;             // 0 (node A) or 2 (node B)
    float* stp = (float*)(ws + OFF_ST);
    const int g = batch[node];
    atomicAdd(&stp[g],       red[wv][0] + red[wv+1][0]);
    atomicAdd(&stp[64 + g],  red[wv][1] + red[wv+1][1]);
    atomicAdd(&stp[128 + g], red[wv][2] + red[wv+1][2]);
    atomicAdd(&stp[192 + g], 1.f);
  }
}

// ---------------------------------------------------------------------------
// kfinal: group-norm + residual add + interleave into output layout.
// Group statistics computed inline from the raw accumulators.
// ---------------------------------------------------------------------------
__global__ __launch_bounds__(256) void kfinal(char* __restrict__ ws, const int* __restrict__ batch,
    const float* __restrict__ lnw0, const float* __restrict__ lnb0, const float* __restrict__ lnw1,
    float* __restrict__ outp)
{
  const int id = blockIdx.x*256 + threadIdx.x;   // < 4096*512
  const int n = id >> 9, c = id & 511;
  const float* st = (const float*)(ws + OFF_ST);
  const int g = batch[n];
  const float cnt = fmaxf(st[192 + g], 1.f);
  float val;
  if (c < 128) {
    const float* y0 = (const float*)(ws + OFF_Y0);
    const float* o0 = (const float*)(ws + OFF_O0);
    float m0   = st[g] / (cnt * 128.f);
    float var0 = st[64 + g] / (cnt * 128.f) - m0*m0;
    float inv0 = 1.f / (sqrtf(fmaxf(var0, 0.f)) + LN_EPS);
    val = (y0[(size_t)n*128 + c] - m0) * inv0 * lnw0[c] + lnb0[c] + o0[(size_t)n*128 + c];
  } else {
    int cc = c - 128, w = cc / 3, i = cc - w*3;
    const float* y1 = (const float*)(ws + OFF_Y1);
    const float* o1 = (const float*)(ws + OFF_O1);
    float inv1 = 1.f / (sqrtf(fmaxf(st[128 + g] / (cnt * 384.f), 0.f)) + LN_EPS);
    val = y1[(size_t)i*524288 + (size_t)n*128 + w] * inv1 * lnw1[w]
        + o1[(size_t)i*524288 + (size_t)n*128 + w];
  }
  outp[id] = val;
}

// ---------------------------------------------------------------------------
extern "C" void kernel_launch(void* const* d_in, const int* in_sizes, int n_in,
                              void* d_out, int out_size, void* d_ws, size_t ws_size,
                              hipStream_t stream)
{
  const float* nfh   = (const float*)d_in[0];
  const float* nfu   = (const float*)d_in[1];
  const float* oneh  = (const float*)d_in[2];
  const int*   batch = (const int*)d_in[3];
  const float* Wh0   = (const float*)d_in[4];
  const float* Wh1   = (const float*)d_in[5];
  const float* Wu0   = (const float*)d_in[6];
  const float* Wu1   = (const float*)d_in[7];
  const float* Wt00  = (const float*)d_in[8];
  const float* Wt11  = (const float*)d_in[9];
  const float* Wt01  = (const float*)d_in[10];
  const float* Wt10  = (const float*)d_in[11];
  const float* Wp0   = (const float*)d_in[12];
  const float* bp0   = (const float*)d_in[13];
  const float* Wp1   = (const float*)d_in[14];
  const float* Wsc0  = (const float*)d_in[15];
  const float* Wsc1  = (const float*)d_in[16];
  const float* lnw0  = (const float*)d_in[17];
  const float* lnb0  = (const float*)d_in[18];
  const float* lnw1  = (const float*)d_in[19];
  const float* Ws0   = (const float*)d_in[20];
  const float* bs0   = (const float*)d_in[21];
  const float* Ws1   = (const float*)d_in[22];
  char* ws = (char*)d_ws;

  if (ws_size < WS_NEED) {
    // Signal: workspace too small (distinct failure signature, no OOB writes)
    hipMemsetAsync(d_out, 0, (size_t)out_size * sizeof(float), stream);
    return;
  }

  kconv<<<1560, 256, 0, stream>>>(nfh, nfu, oneh, Wt00, Wt11, Wt01, Wt10,
                                  Wh0, Wh1, Wu0, Wu1, Wp0, Wp1, Ws0, Ws1, ws);
  kprep<<<256, 256, 0, stream>>>(ws);
  kbig<<<704, 256, 0, stream>>>(ws);
  kreduce<<<2048, 256, 0, stream>>>(ws);
  ktail<<<256, 256, 0, stream>>>(ws, bp0, bs0);
  kscstats<<<2048, 256, 0, stream>>>(ws, nfh, Wsc0, Wsc1, batch);
  kfinal<<<8192, 256, 0, stream>>>(ws, batch, lnw0, lnb0, lnw1, (float*)d_out);
}

// Round 4
// 341.646 us; speedup vs baseline: 1.1214x; 1.1214x over previous
//
#include <hip/hip_runtime.h>
#include <cstdint>
#include <cstddef>

// ---------------------------------------------------------------------------
// NodeDegreeExpansionBlock: fused MFMA implementation for gfx950.
// Key idea: every big contraction is  (rank-1-synthesized A) @ (dense B),
// A[n, u*64+v] = p[n,u]*q[n,v].  A-frags built in registers (pk f16 mul),
// B pre-converted to fp16 in MFMA-fragment order -> direct global b128 loads,
// no LDS, no barriers in the K loop.
// R4 (consolidation):
//  - kbig reverted to the R0-proven 448-block inner loop (132us measured).
//  - partials stored fp16 (sigma~90 -> quantization ~6e-4 on z0 after INV_TP;
//    halves kbig epilogue writes + kreduce reads).
//  - kconv big-B conversion via LDS transpose: coalesced float4 stage of the
//    64x128 f32 slice (LDS pitch 130 -> 2-way = free), frag-order pack reads
//    from LDS instead of 1KB-strided scalar global loads.
//  - h1/u1 deinterleave: one thread reads 3 contiguous floats, writes all 3
//    i-planes (no 3x re-read of the strided source).
//  - kprep fusion kept. 7 dispatches.
// ---------------------------------------------------------------------------

typedef _Float16 half8 __attribute__((ext_vector_type(8)));
typedef _Float16 half4v __attribute__((ext_vector_type(4)));
typedef float f32x4 __attribute__((ext_vector_type(4)));

static constexpr float INV_H  = 0.08838834764831845f;   // 1/sqrt(128)
static constexpr float INV_U  = 0.125f;                 // 1/sqrt(64)
static constexpr float INV_TP = 0.0078125f;             // 1/sqrt(2*128*64)
static constexpr float INV_SC = 0.02795084971874737f;   // 1/sqrt(128*10)
static constexpr float RSQRT3 = 0.5773502691896258f;
static constexpr float LN_EPS = 1e-5f;

// ---- workspace layout (bytes) ----
static constexpr size_t OFF_BZ0 = 0;                     // fp16 frag-ordered [nt(2)][u(256)] 16KB tiles
static constexpr size_t OFF_BZ1 = OFF_BZ0 + 8388608;     // fp16 frag-ordered [u(256)] 16KB tiles
static constexpr size_t OFF_WH0 = OFF_BZ1 + 4194304;
static constexpr size_t OFF_WH1 = OFF_WH0 + 32768;
static constexpr size_t OFF_WU0 = OFF_WH1 + 32768;
static constexpr size_t OFF_WU1 = OFF_WU0 + 8192;
static constexpr size_t OFF_WP0 = OFF_WU1 + 8192;
static constexpr size_t OFF_WP1 = OFF_WP0 + 32768;
static constexpr size_t OFF_WS0 = OFF_WP1 + 32768;
static constexpr size_t OFF_WS1 = OFF_WS0 + 32768;
static constexpr size_t OFF_H0F = OFF_WS1 + 32768;       // f16 (4096,128)
static constexpr size_t OFF_H1F = OFF_H0F + 1048576;     // f16 3 planes (4096,128)
static constexpr size_t OFF_U0F = OFF_H1F + 3145728;     // f16 (4096,64)
static constexpr size_t OFF_U1F = OFF_U0F + 524288;      // f16 3 planes (4096,64)
static constexpr size_t OFF_HP0 = OFF_U1F + 1572864;     // f16 (4096,128)
static constexpr size_t OFF_HP1 = OFF_HP0 + 1048576;     // f16 3 planes
static constexpr size_t OFF_UP0 = OFF_HP1 + 3145728;     // f16 (4096,64)
static constexpr size_t OFF_UP1 = OFF_UP0 + 524288;      // f16 3 planes
static constexpr size_t OFF_SF  = OFF_UP1 + 1572864;     // f16 (4096,128) silu(z0a)
static constexpr size_t OFF_VF  = OFF_SF + 1048576;      // f16 3 planes v = z1*g
static constexpr size_t OFF_PZ0 = OFF_VF + 3145728;      // f16 4 x (4096,256) z0 partials (region sized for f32, half used)
static constexpr size_t OFF_PZ1 = OFF_PZ0 + 16777216;    // f16 2 x (12288,128) z1 partials
static constexpr size_t OFF_Y0  = OFF_PZ1 + 12582912;    // f32 (4096,128)
static constexpr size_t OFF_Y1  = OFF_Y0 + 2097152;      // f32 3 planes (4096,128)
static constexpr size_t OFF_O0  = OFF_Y1 + 6291456;      // f32 (4096,128)
static constexpr size_t OFF_O1  = OFF_O0 + 2097152;      // f32 3 planes
static constexpr size_t OFF_SP  = OFF_O1 + 6291456;      // int (4096)
static constexpr size_t OFF_ST  = OFF_SP + 16384;        // f32 stats: S0,SS0,SS1,CNT (64 each)
static constexpr size_t WS_NEED = OFF_ST + 2048;

// ---------------------------------------------------------------------------
// kconv: all weight conversions (fp32 -> fp16, fragment-ordered), input
// converts/deinterleaves, species argmax, stats-buffer zeroing.
// Frag-ordered big-B tile (16KB per (nt,u)): chunk ch=f*2+c, lane, j holds
// B[w=f*16+(lane&15)][k_in_u = c*32+(lane>>4)*8+j].
// Big-B path: coalesced float4 stage of the 64-row x 128-col f32 slice into
// LDS (pitch 130: quad stride 8*130 mod 32 = 16 -> 2-way, free), then
// frag-order pack reads 8 floats from LDS per half8 chunk.
// ---------------------------------------------------------------------------
__global__ __launch_bounds__(256) void kconv(
    const float* __restrict__ nfh, const float* __restrict__ nfu,
    const float* __restrict__ onehot,
    const float* __restrict__ Wt00, const float* __restrict__ Wt11,
    const float* __restrict__ Wt01, const float* __restrict__ Wt10,
    const float* __restrict__ Wh0, const float* __restrict__ Wh1,
    const float* __restrict__ Wu0, const float* __restrict__ Wu1,
    const float* __restrict__ Wp0, const float* __restrict__ Wp1,
    const float* __restrict__ Ws0, const float* __restrict__ Ws1,
    char* __restrict__ ws)
{
  const int bid = blockIdx.x, t = threadIdx.x;
  if (bid < 768) {
    __shared__ float lds[64 * 130];
    _Float16* dst;
    int u, nt = 0;
    const bool isz0 = bid < 512;
    if (isz0) { nt = bid >> 8; u = bid & 255; dst = (_Float16*)(ws + OFF_BZ0) + ((size_t)nt*256 + (size_t)u)*8192; }
    else      { u = bid - 512;               dst = (_Float16*)(ws + OFF_BZ1) + (size_t)u*8192; }

    // pick source matrix / row base / column offset / scale
    const float* src; int rowpitch, c0; float scale = 1.f;
    if (isz0) {
      rowpitch = 256; c0 = nt*128;
      if (u < 128) { src = Wt00 + (size_t)(u*64)*256; }
      else         { src = Wt11 + (size_t)((u-128)*64)*256; scale = RSQRT3; }
    } else {
      rowpitch = 128; c0 = 0;
      if (u < 128) { src = Wt01 + (size_t)(u*64)*128; }
      else         { src = Wt10 + (size_t)((u-128)*64)*128; }
    }

    // stage: 64 rows x 128 cols, coalesced float4 (2048 float4s, 8/thread)
    #pragma unroll
    for (int it = 0; it < 8; ++it) {
      int gi = it*256 + t;
      int row = gi >> 5, c4 = gi & 31;
      const float4 v = *(const float4*)(src + (size_t)row*rowpitch + c0 + c4*4);
      float* dl = lds + row*130 + c4*4;
      dl[0] = v.x; dl[1] = v.y; dl[2] = v.z; dl[3] = v.w;
    }
    __syncthreads();

    // pack: 1024 half8 chunks, frag order
    for (int it = 0; it < 4; ++it) {
      int chunk = it*256 + t;               // 0..1023
      int lane = chunk & 63, ch = chunk >> 6;
      int f = ch >> 1, c = ch & 1;
      int w = f*16 + (lane & 15);
      int v0 = c*32 + (lane >> 4)*8;
      half8 o;
      #pragma unroll
      for (int j = 0; j < 8; ++j)
        o[j] = (_Float16)(lds[(v0 + j)*130 + w] * scale);
      *(half8*)(dst + (size_t)chunk*8) = o;
    }
  } else if (bid < 776) {
    // small weights -> frag order: chunk q = (c*(N/16)+f)*64+lane,
    // value = W[k=c*32+(lane>>4)*8+j][n=f*16+(lane&15)]
    int mat = bid - 768;
    const float* src; size_t doff; int K, N;
    switch (mat) {
      case 0: src = Wh0; doff = OFF_WH0; K = 128; N = 128; break;
      case 1: src = Wh1; doff = OFF_WH1; K = 128; N = 128; break;
      case 2: src = Wu0; doff = OFF_WU0; K = 64;  N = 64;  break;
      case 3: src = Wu1; doff = OFF_WU1; K = 64;  N = 64;  break;
      case 4: src = Wp0; doff = OFF_WP0; K = 128; N = 128; break;
      case 5: src = Wp1; doff = OFF_WP1; K = 128; N = 128; break;
      case 6: src = Ws0; doff = OFF_WS0; K = 128; N = 128; break;
      default: src = Ws1; doff = OFF_WS1; K = 128; N = 128; break;
    }
    _Float16* d = (_Float16*)(ws + doff);
    const int nfr = N >> 4;
    const int chunks = (K*N) >> 3;
    for (int qd = t; qd < chunks; qd += 256) {
      int lane = qd & 63, cf = qd >> 6;
      int f = cf % nfr, c = cf / nfr;
      int col = f*16 + (lane & 15);
      int k0 = c*32 + (lane >> 4)*8;
      half8 o;
      #pragma unroll
      for (int j = 0; j < 8; ++j) o[j] = (_Float16)src[(size_t)(k0 + j)*N + col];
      *(half8*)(d + (size_t)qd*8) = o;
    }
  } else if (bid < 1544) {
    // input fp32 -> fp16 converts / i-plane deinterleaves
    const int stride = 768*256;
    const int base = (bid - 776)*256 + t;
    _Float16* h0f = (_Float16*)(ws + OFF_H0F);
    _Float16* h1f = (_Float16*)(ws + OFF_H1F);
    _Float16* u0f = (_Float16*)(ws + OFF_U0F);
    _Float16* u1f = (_Float16*)(ws + OFF_U1F);
    // h0: vectorized x4 (131072 items)
    for (int vid = base; vid < 131072; vid += stride) {
      int n = vid >> 5, c4 = (vid & 31)*4;
      const float4 v = *(const float4*)(nfh + (size_t)n*512 + c4);
      half4v o = { (_Float16)v.x, (_Float16)v.y, (_Float16)v.z, (_Float16)v.w };
      *(half4v*)(h0f + (size_t)vid*4) = o;
    }
    // u0: vectorized x4 (65536 items)
    for (int vid = base; vid < 65536; vid += stride) {
      int n = vid >> 4, c4 = (vid & 15)*4;
      const float4 v = *(const float4*)(nfu + (size_t)n*256 + c4);
      half4v o = { (_Float16)v.x, (_Float16)v.y, (_Float16)v.z, (_Float16)v.w };
      *(half4v*)(u0f + (size_t)vid*4) = o;
    }
    // h1: one thread reads 3 contiguous floats, writes 3 planes (524288 pairs)
    for (int id = base; id < 524288; id += stride) {
      int n = id >> 7, u = id & 127;
      const float* s = nfh + (size_t)n*512 + 128 + u*3;
      h1f[id]            = (_Float16)s[0];
      h1f[524288 + id]   = (_Float16)s[1];
      h1f[1048576 + id]  = (_Float16)s[2];
    }
    // u1: same (262144 pairs)
    for (int id = base; id < 262144; id += stride) {
      int n = id >> 6, v = id & 63;
      const float* s = nfu + (size_t)n*256 + 64 + v*3;
      u1f[id]            = (_Float16)s[0];
      u1f[262144 + id]   = (_Float16)s[1];
      u1f[524288 + id]   = (_Float16)s[2];
    }
  } else {
    int node = (bid - 1544)*256 + t;
    const float* row = onehot + (size_t)node*10;
    int best = 0; float bv = row[0];
    #pragma unroll
    for (int s = 1; s < 10; ++s) { float v = row[s]; if (v > bv) { bv = v; best = s; } }
    ((int*)(ws + OFF_SP))[node] = best;
    if (bid == 1544) {           // zero group-stats accumulators (replaces memset)
      float* stz = (float*)(ws + OFF_ST);
      stz[t] = 0.f; stz[t + 256] = 0.f;
    }
  }
}

// ---------------------------------------------------------------------------
// gemm_small_body: C[n, m] = scale * sum_k A[n,k] * W[k,m] (+bias), MFMA
// 16x16x32. 128 nodes per block, 4 waves x 32 rows. A: f16 (n,K) rows.
// W: frag-ordered. MODE 0: h-family prep (f16 out); MODE 1: u-family prep
// (f16 out); MODE 2: tail GEMMs (f32 out, optional bias).
// ---------------------------------------------------------------------------
template<int KK, int NO, int MODE>
__device__ __forceinline__ void gemm_small_body(char* __restrict__ ws,
    const float* __restrict__ bp0, const float* __restrict__ bs0,
    int bid, int t)
{
  constexpr int NT = NO / 16;
  const int lane = t & 63, wid = t >> 6;
  const int quad = lane >> 4, l15 = lane & 15;
  const int job = bid >> 5, n0 = (bid & 31) << 7;

  const _Float16 *A, *W;
  _Float16* oh = nullptr; float* of = nullptr;
  const float* bias = nullptr;
  float scale;
  if constexpr (MODE == 0) {
    scale = INV_H;
    if (job == 0) { A = (const _Float16*)(ws + OFF_H0F); W = (const _Float16*)(ws + OFF_WH0); oh = (_Float16*)(ws + OFF_HP0); }
    else {
      A = (const _Float16*)(ws + OFF_H1F) + (size_t)(job-1)*524288;
      W = (const _Float16*)(ws + OFF_WH1);
      oh = (_Float16*)(ws + OFF_HP1) + (size_t)(job-1)*524288;
    }
  } else if constexpr (MODE == 1) {
    scale = INV_U;
    if (job == 0) { A = (const _Float16*)(ws + OFF_U0F); W = (const _Float16*)(ws + OFF_WU0); oh = (_Float16*)(ws + OFF_UP0); }
    else {
      A = (const _Float16*)(ws + OFF_U1F) + (size_t)(job-1)*262144;
      W = (const _Float16*)(ws + OFF_WU1);
      oh = (_Float16*)(ws + OFF_UP1) + (size_t)(job-1)*262144;
    }
  } else {
    scale = INV_H;
    switch (job) {
      case 0: A = (const _Float16*)(ws + OFF_SF);  W = (const _Float16*)(ws + OFF_WP0); of = (float*)(ws + OFF_Y0); bias = bp0; break;
      case 1: A = (const _Float16*)(ws + OFF_H0F); W = (const _Float16*)(ws + OFF_WS0); of = (float*)(ws + OFF_O0); bias = bs0; break;
      case 2: case 3: case 4:
        A = (const _Float16*)(ws + OFF_VF) + (size_t)(job-2)*524288;
        W = (const _Float16*)(ws + OFF_WP1);
        of = (float*)(ws + OFF_Y1) + (size_t)(job-2)*524288; break;
      default:
        A = (const _Float16*)(ws + OFF_H1F) + (size_t)(job-5)*524288;
        W = (const _Float16*)(ws + OFF_WS1);
        of = (float*)(ws + OFF_O1) + (size_t)(job-5)*524288; break;
    }
  }

  f32x4 acc[2][NT];
  const f32x4 zz = {0.f, 0.f, 0.f, 0.f};
  #pragma unroll
  for (int mf = 0; mf < 2; ++mf)
    #pragma unroll
    for (int nf = 0; nf < NT; ++nf) acc[mf][nf] = zz;

  #pragma unroll
  for (int kc = 0; kc < KK/32; ++kc) {
    half8 a[2];
    #pragma unroll
    for (int mf = 0; mf < 2; ++mf)
      a[mf] = *(const half8*)(A + (size_t)(n0 + wid*32 + mf*16 + l15)*KK + kc*32 + quad*8);
    #pragma unroll
    for (int nf = 0; nf < NT; ++nf) {
      half8 b = *(const half8*)(W + (size_t)(kc*NT + nf)*512 + lane*8);
      #pragma unroll
      for (int mf = 0; mf < 2; ++mf)
        acc[mf][nf] = __builtin_amdgcn_mfma_f32_16x16x32_f16(a[mf], b, acc[mf][nf], 0, 0, 0);
    }
  }

  #pragma unroll
  for (int mf = 0; mf < 2; ++mf)
    #pragma unroll
    for (int nf = 0; nf < NT; ++nf) {
      int col = nf*16 + l15;
      float bv = bias ? bias[col] : 0.f;
      #pragma unroll
      for (int r = 0; r < 4; ++r) {
        int row = n0 + wid*32 + mf*16 + quad*4 + r;
        float v = acc[mf][nf][r] * scale + bv;
        if constexpr (MODE < 2) oh[(size_t)row*NO + col] = (_Float16)v;
        else                    of[(size_t)row*NO + col] = v;
      }
    }
}

// kprep: MODE0 (h-family, 128 blocks) + MODE1 (u-family, 128 blocks) fused.
__global__ __launch_bounds__(256) void kprep(char* __restrict__ ws)
{
  if (blockIdx.x < 128) gemm_small_body<128,128,0>(ws, nullptr, nullptr, blockIdx.x, threadIdx.x);
  else                  gemm_small_body<64, 64, 1>(ws, nullptr, nullptr, blockIdx.x - 128, threadIdx.x);
}

// ktail: MODE2 (8 tail GEMM jobs, 256 blocks).
__global__ __launch_bounds__(256) void ktail(char* __restrict__ ws,
    const float* __restrict__ bp0, const float* __restrict__ bs0)
{
  gemm_small_body<128,128,2>(ws, bp0, bs0, blockIdx.x, threadIdx.x);
}

// ---------------------------------------------------------------------------
// kbig: the bilinear GEMMs. 448 uniform blocks, each a 128x128 tile over
// K=8192 (128 u-steps): A[n, u*64+v] = p[n,u]*q[n,v] synthesized in regs,
// B read directly from frag-ordered fp16 global. No LDS, no barriers.
// (R0-proven inner loop, 80 VGPR.)  Partials stored fp16.
//   bid<256:  z0 partials: mt(32) x nt(2) x kj(4)  [kj0: hp0*up0 @ Wt00;
//             kj1..3: hp1_i*up1_i @ Wt11/sqrt3]
//   bid>=256: z1 partials (i stacked on M): mt(96) x kj(2)
//             [kj0: hp0*up1_i @ Wt01; kj1: hp1_i*up0 @ Wt10]
// ---------------------------------------------------------------------------
__global__ __launch_bounds__(256, 2) void kbig(char* __restrict__ ws)
{
  const int bid = blockIdx.x, t = threadIdx.x;
  const int lane = t & 63, wid = t >> 6;
  const int wy = wid >> 1, wx = wid & 1;
  const int quad = lane >> 4, l15 = lane & 15;

  const _Float16* hp0 = (const _Float16*)(ws + OFF_HP0);
  const _Float16* hp1 = (const _Float16*)(ws + OFF_HP1);
  const _Float16* up0 = (const _Float16*)(ws + OFF_UP0);
  const _Float16* up1 = (const _Float16*)(ws + OFF_UP1);

  const _Float16 *p, *q, *B0;
  _Float16* out; int opitch; size_t obase; int node0;
  if (bid < 256) {
    int mt = bid >> 3, nt = (bid >> 2) & 1, kj = bid & 3;
    node0 = mt << 7;
    if (kj == 0) { p = hp0; q = up0; }
    else { p = hp1 + (size_t)(kj-1)*524288; q = up1 + (size_t)(kj-1)*262144; }
    B0 = (const _Float16*)(ws + OFF_BZ0) + (size_t)nt*2097152 + (kj ? (size_t)1048576 : (size_t)0);
    out = (_Float16*)(ws + OFF_PZ0) + (size_t)kj*1048576;
    obase = (size_t)node0*256 + (size_t)nt*128;
    opitch = 256;
  } else {
    int b2 = bid - 256, mt = b2 >> 1, kj = b2 & 1, i = mt >> 5;
    node0 = (mt & 31) << 7;
    if (kj == 0) { p = hp0; q = up1 + (size_t)i*262144; }
    else         { p = hp1 + (size_t)i*524288; q = up0; }
    B0 = (const _Float16*)(ws + OFF_BZ1) + (kj ? (size_t)1048576 : (size_t)0);
    out = (_Float16*)(ws + OFF_PZ1) + (size_t)kj*1572864;
    obase = (size_t)mt*16384;
    opitch = 128;
  }

  // q fragments: fixed for the whole K loop (A[m][k]=p[m,u]*q[m,v], v=k&63)
  half8 qf[4][2];
  #pragma unroll
  for (int mf = 0; mf < 4; ++mf)
    #pragma unroll
    for (int c = 0; c < 2; ++c)
      qf[mf][c] = *(const half8*)(q + (size_t)(node0 + wy*64 + mf*16 + l15)*64 + c*32 + quad*8);

  f32x4 acc[4][4];
  const f32x4 zz = {0.f, 0.f, 0.f, 0.f};
  #pragma unroll
  for (int mf = 0; mf < 4; ++mf)
    #pragma unroll
    for (int nf = 0; nf < 4; ++nf) acc[mf][nf] = zz;

  const _Float16* prow = p + (size_t)(node0 + wy*64 + l15)*128;
  const _Float16* Bw = B0 + (size_t)wx*4096 + (size_t)lane*8;

  for (int u4 = 0; u4 < 32; ++u4) {
    half4v pw[4];
    #pragma unroll
    for (int mf = 0; mf < 4; ++mf)
      pw[mf] = *(const half4v*)(prow + (size_t)mf*2048 + u4*4);
    #pragma unroll
    for (int uu = 0; uu < 4; ++uu) {
      const _Float16* Bu = Bw + (size_t)(u4*4 + uu)*8192;
      half8 bf[2][4];
      #pragma unroll
      for (int c = 0; c < 2; ++c)
        #pragma unroll
        for (int nf = 0; nf < 4; ++nf)
          bf[c][nf] = *(const half8*)(Bu + (size_t)((nf*2 + c)*512));
      #pragma unroll
      for (int mf = 0; mf < 4; ++mf) {
        const _Float16 ps = pw[mf][uu];
        const half8 pv = {ps, ps, ps, ps, ps, ps, ps, ps};
        #pragma unroll
        for (int c = 0; c < 2; ++c) {
          half8 a = qf[mf][c] * pv;
          #pragma unroll
          for (int nf = 0; nf < 4; ++nf)
            acc[mf][nf] = __builtin_amdgcn_mfma_f32_16x16x32_f16(a, bf[c][nf], acc[mf][nf], 0, 0, 0);
        }
      }
    }
  }

  #pragma unroll
  for (int mf = 0; mf < 4; ++mf)
    #pragma unroll
    for (int nf = 0; nf < 4; ++nf) {
      int col = wx*64 + nf*16 + l15;
      #pragma unroll
      for (int r = 0; r < 4; ++r) {
        int row = wy*64 + mf*16 + quad*4 + r;
        out[obase + (size_t)row*opitch + col] = (_Float16)acc[mf][nf][r];
      }
    }
}

// ---------------------------------------------------------------------------
// kreduce: sum fp16 K-partials, apply inv_tp, silu/sigmoid gates, emit s,v.
// ---------------------------------------------------------------------------
__global__ __launch_bounds__(256) void kreduce(char* __restrict__ ws)
{
  const int id = blockIdx.x*256 + threadIdx.x;   // < 4096*128
  const int n = id >> 7, w = id & 127;
  const _Float16* pz0 = (const _Float16*)(ws + OFF_PZ0);
  const _Float16* pz1 = (const _Float16*)(ws + OFF_PZ1);
  _Float16* sf = (_Float16*)(ws + OFF_SF);
  _Float16* vf = (_Float16*)(ws + OFF_VF);
  const size_t b = (size_t)n*256;
  float zs = ((float)pz0[b + w] + (float)pz0[1048576 + b + w]
            + (float)pz0[2097152 + b + w] + (float)pz0[3145728 + b + w]) * INV_TP;
  float zg = ((float)pz0[b + 128 + w] + (float)pz0[1048576 + b + 128 + w]
            + (float)pz0[2097152 + b + 128 + w] + (float)pz0[3145728 + b + 128 + w]) * INV_TP;
  float s = zs / (1.f + __expf(-zs));
  float g = 1.f / (1.f + __expf(-zg));
  sf[id] = (_Float16)s;
  #pragma unroll
  for (int i = 0; i < 3; ++i) {
    size_t r = ((size_t)i*4096 + (size_t)n)*128 + w;
    float z1v = ((float)pz1[r] + (float)pz1[1572864 + r]) * INV_TP;
    vf[(size_t)i*524288 + (size_t)n*128 + w] = (_Float16)(z1v * g);
  }
}

// ---------------------------------------------------------------------------
// kscstats: species-gathered skip terms, y0/y1 += inv_sc * h @ Wsc[:,sp,:],
// fused with the per-group stat accumulation (y values kept in registers).
// 2 nodes per block (waves 0,1 -> node A; waves 2,3 -> node B).
// ---------------------------------------------------------------------------
__global__ __launch_bounds__(256) void kscstats(char* __restrict__ ws,
    const float* __restrict__ nfh,
    const float* __restrict__ Wsc0, const float* __restrict__ Wsc1,
    const int* __restrict__ batch)
{
  const int t = threadIdx.x;
  const int node = blockIdx.x*2 + (t >> 7);
  const int w = t & 127;
  const int sp = ((const int*)(ws + OFF_SP))[node];
  const float* h = nfh + (size_t)node*512;
  float a0 = 0.f, a10 = 0.f, a11 = 0.f, a12 = 0.f;
  for (int u = 0; u < 128; ++u) {
    const size_t wi = (size_t)(u*10 + sp)*128 + w;
    float w0 = Wsc0[wi];
    float w1 = Wsc1[wi];
    a0 += h[u] * w0;
    a10 += h[128 + u*3 + 0] * w1;
    a11 += h[128 + u*3 + 1] * w1;
    a12 += h[128 + u*3 + 2] * w1;
  }
  float* y0 = (float*)(ws + OFF_Y0);
  float* y1 = (float*)(ws + OFF_Y1);
  const size_t i0 = (size_t)node*128 + w;
  float y0n  = y0[i0]           + INV_SC * a0;
  float y1n0 = y1[i0]           + INV_SC * a10;
  float y1n1 = y1[524288 + i0]  + INV_SC * a11;
  float y1n2 = y1[1048576 + i0] + INV_SC * a12;
  y0[i0] = y0n;
  y1[i0] = y1n0;
  y1[524288 + i0]  = y1n1;
  y1[1048576 + i0] = y1n2;

  float s0 = y0n, ss0 = y0n*y0n, ss1 = y1n0*y1n0 + y1n1*y1n1 + y1n2*y1n2;
  #pragma unroll
  for (int m = 1; m < 64; m <<= 1) {
    s0  += __shfl_xor(s0, m, 64);
    ss0 += __shfl_xor(ss0, m, 64);
    ss1 += __shfl_xor(ss1, m, 64);
  }
  __shared__ float red[4][3];
  if ((t & 63) == 0) {
    red[t >> 6][0] = s0; red[t >> 6][1] = ss0; red[t >> 6][2] = ss1;
  }
  __syncthreads();
  if ((t & 127) == 0) {
    const int wv = t >> 6;             // 0 (node A) or 2 (node B)
    float* stp = (float*)(ws + OFF_ST);
    const int g = batch[node];
    atomicAdd(&stp[g],       red[wv][0] + red[wv+1][0]);
    atomicAdd(&stp[64 + g],  red[wv][1] + red[wv+1][1]);
    atomicAdd(&stp[128 + g], red[wv][2] + red[wv+1][2]);
    atomicAdd(&stp[192 + g], 1.f);
  }
}

// ---------------------------------------------------------------------------
// kfinal: group-norm + residual add + interleave into output layout.
// Group statistics computed inline from the raw accumulators.
// ---------------------------------------------------------------------------
__global__ __launch_bounds__(256) void kfinal(char* __restrict__ ws, const int* __restrict__ batch,
    const float* __restrict__ lnw0, const float* __restrict__ lnb0, const float* __restrict__ lnw1,
    float* __restrict__ outp)
{
  const int id = blockIdx.x*256 + threadIdx.x;   // < 4096*512
  const int n = id >> 9, c = id & 511;
  const float* st = (const float*)(ws + OFF_ST);
  const int g = batch[n];
  const float cnt = fmaxf(st[192 + g], 1.f);
  float val;
  if (c < 128) {
    const float* y0 = (const float*)(ws + OFF_Y0);
    const float* o0 = (const float*)(ws + OFF_O0);
    float m0   = st[g] / (cnt * 128.f);
    float var0 = st[64 + g] / (cnt * 128.f) - m0*m0;
    float inv0 = 1.f / (sqrtf(fmaxf(var0, 0.f)) + LN_EPS);
    val = (y0[(size_t)n*128 + c] - m0) * inv0 * lnw0[c] + lnb0[c] + o0[(size_t)n*128 + c];
  } else {
    int cc = c - 128, w = cc / 3, i = cc - w*3;
    const float* y1 = (const float*)(ws + OFF_Y1);
    const float* o1 = (const float*)(ws + OFF_O1);
    float inv1 = 1.f / (sqrtf(fmaxf(st[128 + g] / (cnt * 384.f), 0.f)) + LN_EPS);
    val = y1[(size_t)i*524288 + (size_t)n*128 + w] * inv1 * lnw1[w]
        + o1[(size_t)i*524288 + (size_t)n*128 + w];
  }
  outp[id] = val;
}

// ---------------------------------------------------------------------------
extern "C" void kernel_launch(void* const* d_in, const int* in_sizes, int n_in,
                              void* d_out, int out_size, void* d_ws, size_t ws_size,
                              hipStream_t stream)
{
  const float* nfh   = (const float*)d_in[0];
  const float* nfu   = (const float*)d_in[1];
  const float* oneh  = (const float*)d_in[2];
  const int*   batch = (const int*)d_in[3];
  const float* Wh0   = (const float*)d_in[4];
  const float* Wh1   = (const float*)d_in[5];
  const float* Wu0   = (const float*)d_in[6];
  const float* Wu1   = (const float*)d_in[7];
  const float* Wt00  = (const float*)d_in[8];
  const float* Wt11  = (const float*)d_in[9];
  const float* Wt01  = (const float*)d_in[10];
  const float* Wt10  = (const float*)d_in[11];
  const float* Wp0   = (const float*)d_in[12];
  const float* bp0   = (const float*)d_in[13];
  const float* Wp1   = (const float*)d_in[14];
  const float* Wsc0  = (const float*)d_in[15];
  const float* Wsc1  = (const float*)d_in[16];
  const float* lnw0  = (const float*)d_in[17];
  const float* lnb0  = (const float*)d_in[18];
  const float* lnw1  = (const float*)d_in[19];
  const float* Ws0   = (const float*)d_in[20];
  const float* bs0   = (const float*)d_in[21];
  const float* Ws1   = (const float*)d_in[22];
  char* ws = (char*)d_ws;

  if (ws_size < WS_NEED) {
    // Signal: workspace too small (distinct failure signature, no OOB writes)
    hipMemsetAsync(d_out, 0, (size_t)out_size * sizeof(float), stream);
    return;
  }

  kconv<<<1560, 256, 0, stream>>>(nfh, nfu, oneh, Wt00, Wt11, Wt01, Wt10,
                                  Wh0, Wh1, Wu0, Wu1, Wp0, Wp1, Ws0, Ws1, ws);
  kprep<<<256, 256, 0, stream>>>(ws);
  kbig<<<448, 256, 0, stream>>>(ws);
  kreduce<<<2048, 256, 0, stream>>>(ws);
  ktail<<<256, 256, 0, stream>>>(ws, bp0, bs0);
  kscstats<<<2048, 256, 0, stream>>>(ws, nfh, Wsc0, Wsc1, batch);
  kfinal<<<8192, 256, 0, stream>>>(ws, batch, lnw0, lnb0, lnw1, (float*)d_out);
}

// Round 6
// 336.184 us; speedup vs baseline: 1.1396x; 1.0162x over previous
//
#include <hip/hip_runtime.h>
#include <cstdint>
#include <cstddef>

// ---------------------------------------------------------------------------
// NodeDegreeExpansionBlock: fused MFMA implementation for gfx950.
// Key idea: every big contraction is  (rank-1-synthesized A) @ (dense B),
// A[n, u*64+v] = p[n,u]*q[n,v].  A-frags built in registers (pk f16 mul),
// B pre-converted to fp16 in MFMA-fragment order -> direct global b128 loads,
// no LDS, no barriers in the K loop.
// R6: R5's asm pipeline FIXED (R5 NaN root cause: (a) pw=pwN v_mov copy read
// in-flight load dests; (b) A-pack placed before the wait that drains p).
//  - u4 loop unrolled x2 with NAMED pwA/pwB ping-pong (no copies);
//  - pack moved AFTER waitcnt + sched_barrier(0) in every phase;
//  - vmcnt queue verified per-phase (8/8/12/12 alternation, never 0 in loop).
//  Everything outside kbig identical to the passing R4 (342us).
// ---------------------------------------------------------------------------

typedef _Float16 half8 __attribute__((ext_vector_type(8)));
typedef _Float16 half4v __attribute__((ext_vector_type(4)));
typedef float f32x4 __attribute__((ext_vector_type(4)));

static constexpr float INV_H  = 0.08838834764831845f;   // 1/sqrt(128)
static constexpr float INV_U  = 0.125f;                 // 1/sqrt(64)
static constexpr float INV_TP = 0.0078125f;             // 1/sqrt(2*128*64)
static constexpr float INV_SC = 0.02795084971874737f;   // 1/sqrt(128*10)
static constexpr float RSQRT3 = 0.5773502691896258f;
static constexpr float LN_EPS = 1e-5f;

// ---- workspace layout (bytes) ----
static constexpr size_t OFF_BZ0 = 0;                     // fp16 frag-ordered [nt(2)][u(256)] 16KB tiles
static constexpr size_t OFF_BZ1 = OFF_BZ0 + 8388608;     // fp16 frag-ordered [u(256)] 16KB tiles
static constexpr size_t OFF_WH0 = OFF_BZ1 + 4194304;
static constexpr size_t OFF_WH1 = OFF_WH0 + 32768;
static constexpr size_t OFF_WU0 = OFF_WH1 + 32768;
static constexpr size_t OFF_WU1 = OFF_WU0 + 8192;
static constexpr size_t OFF_WP0 = OFF_WU1 + 8192;
static constexpr size_t OFF_WP1 = OFF_WP0 + 32768;
static constexpr size_t OFF_WS0 = OFF_WP1 + 32768;
static constexpr size_t OFF_WS1 = OFF_WS0 + 32768;
static constexpr size_t OFF_H0F = OFF_WS1 + 32768;       // f16 (4096,128)
static constexpr size_t OFF_H1F = OFF_H0F + 1048576;     // f16 3 planes (4096,128)
static constexpr size_t OFF_U0F = OFF_H1F + 3145728;     // f16 (4096,64)
static constexpr size_t OFF_U1F = OFF_U0F + 524288;      // f16 3 planes (4096,64)
static constexpr size_t OFF_HP0 = OFF_U1F + 1572864;     // f16 (4096,128)
static constexpr size_t OFF_HP1 = OFF_HP0 + 1048576;     // f16 3 planes
static constexpr size_t OFF_UP0 = OFF_HP1 + 3145728;     // f16 (4096,64)
static constexpr size_t OFF_UP1 = OFF_UP0 + 524288;      // f16 3 planes
static constexpr size_t OFF_SF  = OFF_UP1 + 1572864;     // f16 (4096,128) silu(z0a)
static constexpr size_t OFF_VF  = OFF_SF + 1048576;      // f16 3 planes v = z1*g
static constexpr size_t OFF_PZ0 = OFF_VF + 3145728;      // f16 4 x (4096,256) z0 partials
static constexpr size_t OFF_PZ1 = OFF_PZ0 + 16777216;    // f16 2 x (12288,128) z1 partials
static constexpr size_t OFF_Y0  = OFF_PZ1 + 12582912;    // f32 (4096,128)
static constexpr size_t OFF_Y1  = OFF_Y0 + 2097152;      // f32 3 planes (4096,128)
static constexpr size_t OFF_O0  = OFF_Y1 + 6291456;      // f32 (4096,128)
static constexpr size_t OFF_O1  = OFF_O0 + 2097152;      // f32 3 planes
static constexpr size_t OFF_SP  = OFF_O1 + 6291456;      // int (4096)
static constexpr size_t OFF_ST  = OFF_SP + 16384;        // f32 stats: S0,SS0,SS1,CNT (64 each)
static constexpr size_t WS_NEED = OFF_ST + 2048;

// ---------------------------------------------------------------------------
// kconv: all weight conversions (fp32 -> fp16, fragment-ordered), input
// converts/deinterleaves, species argmax, stats-buffer zeroing.
// ---------------------------------------------------------------------------
__global__ __launch_bounds__(256) void kconv(
    const float* __restrict__ nfh, const float* __restrict__ nfu,
    const float* __restrict__ onehot,
    const float* __restrict__ Wt00, const float* __restrict__ Wt11,
    const float* __restrict__ Wt01, const float* __restrict__ Wt10,
    const float* __restrict__ Wh0, const float* __restrict__ Wh1,
    const float* __restrict__ Wu0, const float* __restrict__ Wu1,
    const float* __restrict__ Wp0, const float* __restrict__ Wp1,
    const float* __restrict__ Ws0, const float* __restrict__ Ws1,
    char* __restrict__ ws)
{
  const int bid = blockIdx.x, t = threadIdx.x;
  if (bid < 768) {
    __shared__ float lds[64 * 130];
    _Float16* dst;
    int u, nt = 0;
    const bool isz0 = bid < 512;
    if (isz0) { nt = bid >> 8; u = bid & 255; dst = (_Float16*)(ws + OFF_BZ0) + ((size_t)nt*256 + (size_t)u)*8192; }
    else      { u = bid - 512;               dst = (_Float16*)(ws + OFF_BZ1) + (size_t)u*8192; }

    const float* src; int rowpitch, c0; float scale = 1.f;
    if (isz0) {
      rowpitch = 256; c0 = nt*128;
      if (u < 128) { src = Wt00 + (size_t)(u*64)*256; }
      else         { src = Wt11 + (size_t)((u-128)*64)*256; scale = RSQRT3; }
    } else {
      rowpitch = 128; c0 = 0;
      if (u < 128) { src = Wt01 + (size_t)(u*64)*128; }
      else         { src = Wt10 + (size_t)((u-128)*64)*128; }
    }

    #pragma unroll
    for (int it = 0; it < 8; ++it) {
      int gi = it*256 + t;
      int row = gi >> 5, c4 = gi & 31;
      const float4 v = *(const float4*)(src + (size_t)row*rowpitch + c0 + c4*4);
      float* dl = lds + row*130 + c4*4;
      dl[0] = v.x; dl[1] = v.y; dl[2] = v.z; dl[3] = v.w;
    }
    __syncthreads();

    for (int it = 0; it < 4; ++it) {
      int chunk = it*256 + t;               // 0..1023
      int lane = chunk & 63, ch = chunk >> 6;
      int f = ch >> 1, c = ch & 1;
      int w = f*16 + (lane & 15);
      int v0 = c*32 + (lane >> 4)*8;
      half8 o;
      #pragma unroll
      for (int j = 0; j < 8; ++j)
        o[j] = (_Float16)(lds[(v0 + j)*130 + w] * scale);
      *(half8*)(dst + (size_t)chunk*8) = o;
    }
  } else if (bid < 776) {
    int mat = bid - 768;
    const float* src; size_t doff; int K, N;
    switch (mat) {
      case 0: src = Wh0; doff = OFF_WH0; K = 128; N = 128; break;
      case 1: src = Wh1; doff = OFF_WH1; K = 128; N = 128; break;
      case 2: src = Wu0; doff = OFF_WU0; K = 64;  N = 64;  break;
      case 3: src = Wu1; doff = OFF_WU1; K = 64;  N = 64;  break;
      case 4: src = Wp0; doff = OFF_WP0; K = 128; N = 128; break;
      case 5: src = Wp1; doff = OFF_WP1; K = 128; N = 128; break;
      case 6: src = Ws0; doff = OFF_WS0; K = 128; N = 128; break;
      default: src = Ws1; doff = OFF_WS1; K = 128; N = 128; break;
    }
    _Float16* d = (_Float16*)(ws + doff);
    const int nfr = N >> 4;
    const int chunks = (K*N) >> 3;
    for (int qd = t; qd < chunks; qd += 256) {
      int lane = qd & 63, cf = qd >> 6;
      int f = cf % nfr, c = cf / nfr;
      int col = f*16 + (lane & 15);
      int k0 = c*32 + (lane >> 4)*8;
      half8 o;
      #pragma unroll
      for (int j = 0; j < 8; ++j) o[j] = (_Float16)src[(size_t)(k0 + j)*N + col];
      *(half8*)(d + (size_t)qd*8) = o;
    }
  } else if (bid < 1544) {
    const int stride = 768*256;
    const int base = (bid - 776)*256 + t;
    _Float16* h0f = (_Float16*)(ws + OFF_H0F);
    _Float16* h1f = (_Float16*)(ws + OFF_H1F);
    _Float16* u0f = (_Float16*)(ws + OFF_U0F);
    _Float16* u1f = (_Float16*)(ws + OFF_U1F);
    for (int vid = base; vid < 131072; vid += stride) {
      int n = vid >> 5, c4 = (vid & 31)*4;
      const float4 v = *(const float4*)(nfh + (size_t)n*512 + c4);
      half4v o = { (_Float16)v.x, (_Float16)v.y, (_Float16)v.z, (_Float16)v.w };
      *(half4v*)(h0f + (size_t)vid*4) = o;
    }
    for (int vid = base; vid < 65536; vid += stride) {
      int n = vid >> 4, c4 = (vid & 15)*4;
      const float4 v = *(const float4*)(nfu + (size_t)n*256 + c4);
      half4v o = { (_Float16)v.x, (_Float16)v.y, (_Float16)v.z, (_Float16)v.w };
      *(half4v*)(u0f + (size_t)vid*4) = o;
    }
    for (int id = base; id < 524288; id += stride) {
      int n = id >> 7, u = id & 127;
      const float* s = nfh + (size_t)n*512 + 128 + u*3;
      h1f[id]            = (_Float16)s[0];
      h1f[524288 + id]   = (_Float16)s[1];
      h1f[1048576 + id]  = (_Float16)s[2];
    }
    for (int id = base; id < 262144; id += stride) {
      int n = id >> 6, v = id & 63;
      const float* s = nfu + (size_t)n*256 + 64 + v*3;
      u1f[id]            = (_Float16)s[0];
      u1f[262144 + id]   = (_Float16)s[1];
      u1f[524288 + id]   = (_Float16)s[2];
    }
  } else {
    int node = (bid - 1544)*256 + t;
    const float* row = onehot + (size_t)node*10;
    int best = 0; float bv = row[0];
    #pragma unroll
    for (int s = 1; s < 10; ++s) { float v = row[s]; if (v > bv) { bv = v; best = s; } }
    ((int*)(ws + OFF_SP))[node] = best;
    if (bid == 1544) {
      float* stz = (float*)(ws + OFF_ST);
      stz[t] = 0.f; stz[t + 256] = 0.f;
    }
  }
}

// ---------------------------------------------------------------------------
// gemm_small_body: C[n, m] = scale * sum_k A[n,k] * W[k,m] (+bias), MFMA
// 16x16x32. 128 nodes per block, 4 waves x 32 rows.
// ---------------------------------------------------------------------------
template<int KK, int NO, int MODE>
__device__ __forceinline__ void gemm_small_body(char* __restrict__ ws,
    const float* __restrict__ bp0, const float* __restrict__ bs0,
    int bid, int t)
{
  constexpr int NT = NO / 16;
  const int lane = t & 63, wid = t >> 6;
  const int quad = lane >> 4, l15 = lane & 15;
  const int job = bid >> 5, n0 = (bid & 31) << 7;

  const _Float16 *A, *W;
  _Float16* oh = nullptr; float* of = nullptr;
  const float* bias = nullptr;
  float scale;
  if constexpr (MODE == 0) {
    scale = INV_H;
    if (job == 0) { A = (const _Float16*)(ws + OFF_H0F); W = (const _Float16*)(ws + OFF_WH0); oh = (_Float16*)(ws + OFF_HP0); }
    else {
      A = (const _Float16*)(ws + OFF_H1F) + (size_t)(job-1)*524288;
      W = (const _Float16*)(ws + OFF_WH1);
      oh = (_Float16*)(ws + OFF_HP1) + (size_t)(job-1)*524288;
    }
  } else if constexpr (MODE == 1) {
    scale = INV_U;
    if (job == 0) { A = (const _Float16*)(ws + OFF_U0F); W = (const _Float16*)(ws + OFF_WU0); oh = (_Float16*)(ws + OFF_UP0); }
    else {
      A = (const _Float16*)(ws + OFF_U1F) + (size_t)(job-1)*262144;
      W = (const _Float16*)(ws + OFF_WU1);
      oh = (_Float16*)(ws + OFF_UP1) + (size_t)(job-1)*262144;
    }
  } else {
    scale = INV_H;
    switch (job) {
      case 0: A = (const _Float16*)(ws + OFF_SF);  W = (const _Float16*)(ws + OFF_WP0); of = (float*)(ws + OFF_Y0); bias = bp0; break;
      case 1: A = (const _Float16*)(ws + OFF_H0F); W = (const _Float16*)(ws + OFF_WS0); of = (float*)(ws + OFF_O0); bias = bs0; break;
      case 2: case 3: case 4:
        A = (const _Float16*)(ws + OFF_VF) + (size_t)(job-2)*524288;
        W = (const _Float16*)(ws + OFF_WP1);
        of = (float*)(ws + OFF_Y1) + (size_t)(job-2)*524288; break;
      default:
        A = (const _Float16*)(ws + OFF_H1F) + (size_t)(job-5)*524288;
        W = (const _Float16*)(ws + OFF_WS1);
        of = (float*)(ws + OFF_O1) + (size_t)(job-5)*524288; break;
    }
  }

  f32x4 acc[2][NT];
  const f32x4 zz = {0.f, 0.f, 0.f, 0.f};
  #pragma unroll
  for (int mf = 0; mf < 2; ++mf)
    #pragma unroll
    for (int nf = 0; nf < NT; ++nf) acc[mf][nf] = zz;

  #pragma unroll
  for (int kc = 0; kc < KK/32; ++kc) {
    half8 a[2];
    #pragma unroll
    for (int mf = 0; mf < 2; ++mf)
      a[mf] = *(const half8*)(A + (size_t)(n0 + wid*32 + mf*16 + l15)*KK + kc*32 + quad*8);
    #pragma unroll
    for (int nf = 0; nf < NT; ++nf) {
      half8 b = *(const half8*)(W + (size_t)(kc*NT + nf)*512 + lane*8);
      #pragma unroll
      for (int mf = 0; mf < 2; ++mf)
        acc[mf][nf] = __builtin_amdgcn_mfma_f32_16x16x32_f16(a[mf], b, acc[mf][nf], 0, 0, 0);
    }
  }

  #pragma unroll
  for (int mf = 0; mf < 2; ++mf)
    #pragma unroll
    for (int nf = 0; nf < NT; ++nf) {
      int col = nf*16 + l15;
      float bv = bias ? bias[col] : 0.f;
      #pragma unroll
      for (int r = 0; r < 4; ++r) {
        int row = n0 + wid*32 + mf*16 + quad*4 + r;
        float v = acc[mf][nf][r] * scale + bv;
        if constexpr (MODE < 2) oh[(size_t)row*NO + col] = (_Float16)v;
        else                    of[(size_t)row*NO + col] = v;
      }
    }
}

// kprep: MODE0 (h-family, 128 blocks) + MODE1 (u-family, 128 blocks) fused.
__global__ __launch_bounds__(256) void kprep(char* __restrict__ ws)
{
  if (blockIdx.x < 128) gemm_small_body<128,128,0>(ws, nullptr, nullptr, blockIdx.x, threadIdx.x);
  else                  gemm_small_body<64, 64, 1>(ws, nullptr, nullptr, blockIdx.x - 128, threadIdx.x);
}

// ktail: MODE2 (8 tail GEMM jobs, 256 blocks).
__global__ __launch_bounds__(256) void ktail(char* __restrict__ ws,
    const float* __restrict__ bp0, const float* __restrict__ bs0)
{
  gemm_small_body<128,128,2>(ws, bp0, bs0, blockIdx.x, threadIdx.x);
}

// ---------------------------------------------------------------------------
// kbig: the bilinear GEMMs. 448 uniform blocks, each a 128x128 tile over
// K=8192 (128 u-steps). Inline-asm pipelined, u4 loop unrolled x2 with
// named pwA/pwB ping-pong (NO register copies of in-flight load dests).
// Every phase: issue loads -> counted s_waitcnt -> sched_barrier(0) ->
// A-pack (reads p AFTER its drain point) -> 32 MFMA. vmcnt queue verified:
//   ph0: +B     wait 8  (drains pA4+A8)   pack pwA, MFMA bufA
//   ph1: +A     wait 8  (drains B8)                 MFMA bufB
//   ph2: +B,pB  wait 12 (drains A8)                 MFMA bufA
//   ph3: +A     wait 12 (drains B8)                 MFMA bufB
//   ph4: +B     wait 8  (drains pB4+A8)   pack pwB, MFMA bufA
//   ph5: +A     wait 8  · ph6: +B,pA wait 12 · ph7: +A wait 12
// Loop invariant entry/exit Q = [p4, A8]. Never drains to 0 in the loop.
// ---------------------------------------------------------------------------
__global__ __launch_bounds__(256, 2) void kbig(char* __restrict__ ws)
{
  const int bid = blockIdx.x, t = threadIdx.x;
  const int lane = t & 63, wid = t >> 6;
  const int wy = wid >> 1, wx = wid & 1;
  const int quad = lane >> 4, l15 = lane & 15;

  const _Float16* hp0 = (const _Float16*)(ws + OFF_HP0);
  const _Float16* hp1 = (const _Float16*)(ws + OFF_HP1);
  const _Float16* up0 = (const _Float16*)(ws + OFF_UP0);
  const _Float16* up1 = (const _Float16*)(ws + OFF_UP1);

  const _Float16 *p, *q, *B0;
  _Float16* out; int opitch; size_t obase; int node0;
  if (bid < 256) {
    int mt = bid >> 3, nt = (bid >> 2) & 1, kj = bid & 3;
    node0 = mt << 7;
    if (kj == 0) { p = hp0; q = up0; }
    else { p = hp1 + (size_t)(kj-1)*524288; q = up1 + (size_t)(kj-1)*262144; }
    B0 = (const _Float16*)(ws + OFF_BZ0) + (size_t)nt*2097152 + (kj ? (size_t)1048576 : (size_t)0);
    out = (_Float16*)(ws + OFF_PZ0) + (size_t)kj*1048576;
    obase = (size_t)node0*256 + (size_t)nt*128;
    opitch = 256;
  } else {
    int b2 = bid - 256, mt = b2 >> 1, kj = b2 & 1, i = mt >> 5;
    node0 = (mt & 31) << 7;
    if (kj == 0) { p = hp0; q = up1 + (size_t)i*262144; }
    else         { p = hp1 + (size_t)i*524288; q = up0; }
    B0 = (const _Float16*)(ws + OFF_BZ1) + (kj ? (size_t)1048576 : (size_t)0);
    out = (_Float16*)(ws + OFF_PZ1) + (size_t)kj*1572864;
    obase = (size_t)mt*16384;
    opitch = 128;
  }

  // q fragments: fixed for the whole K loop (A[m][k]=p[m,u]*q[m,v], v=k&63)
  half8 qf[4][2];
  #pragma unroll
  for (int mf = 0; mf < 4; ++mf)
    #pragma unroll
    for (int c = 0; c < 2; ++c)
      qf[mf][c] = *(const half8*)(q + (size_t)(node0 + wy*64 + mf*16 + l15)*64 + c*32 + quad*8);

  f32x4 acc[4][4];
  const f32x4 zz = {0.f, 0.f, 0.f, 0.f};
  #pragma unroll
  for (int mf = 0; mf < 4; ++mf)
    #pragma unroll
    for (int nf = 0; nf < 4; ++nf) acc[mf][nf] = zz;

  const _Float16* prow = p + (size_t)(node0 + wy*64 + l15)*128;
  const char* Bw = (const char*)(B0 + (size_t)wx*4096 + (size_t)lane*8);

  half8 bufA[8], bufB[8];
  half4v pwA[4], pwB[4];

  // issue 8 B loads for u-step uidx (16KB apart; 8 chunks at 1KB stride)
  auto LDB = [&](half8 (&buf)[8], int uidx) {
    const char* b  = Bw + (size_t)uidx*16384;
    const char* b2 = b + 4096;
    asm volatile("global_load_dwordx4 %0, %1, off"             : "=v"(buf[0]) : "v"(b));
    asm volatile("global_load_dwordx4 %0, %1, off offset:1024" : "=v"(buf[1]) : "v"(b));
    asm volatile("global_load_dwordx4 %0, %1, off offset:2048" : "=v"(buf[2]) : "v"(b));
    asm volatile("global_load_dwordx4 %0, %1, off offset:3072" : "=v"(buf[3]) : "v"(b));
    asm volatile("global_load_dwordx4 %0, %1, off"             : "=v"(buf[4]) : "v"(b2));
    asm volatile("global_load_dwordx4 %0, %1, off offset:1024" : "=v"(buf[5]) : "v"(b2));
    asm volatile("global_load_dwordx4 %0, %1, off offset:2048" : "=v"(buf[6]) : "v"(b2));
    asm volatile("global_load_dwordx4 %0, %1, off offset:3072" : "=v"(buf[7]) : "v"(b2));
  };
  // issue 4 p loads (one half4v per mf) for u4 index
  auto LDP = [&](half4v (&pp)[4], int u4n) {
    #pragma unroll
    for (int mf = 0; mf < 4; ++mf)
      asm volatile("global_load_dwordx2 %0, %1, off"
                   : "=v"(pp[mf]) : "v"(prow + (size_t)mf*2048 + u4n*4));
  };
  // counted wait + fence, THEN pack (p drained), THEN 32 MFMA
  auto MSTEP = [&](half8 (&buf)[8], half4v (&pp)[4], int uu, int deep) {
    if (deep) asm volatile("s_waitcnt vmcnt(12)" ::: "memory");
    else      asm volatile("s_waitcnt vmcnt(8)"  ::: "memory");
    __builtin_amdgcn_sched_barrier(0);
    half8 av[4][2];
    #pragma unroll
    for (int mf = 0; mf < 4; ++mf) {
      const _Float16 ps = pp[mf][uu];
      const half8 pv = {ps, ps, ps, ps, ps, ps, ps, ps};
      #pragma unroll
      for (int c = 0; c < 2; ++c) av[mf][c] = qf[mf][c] * pv;
    }
    #pragma unroll
    for (int mf = 0; mf < 4; ++mf)
      #pragma unroll
      for (int c = 0; c < 2; ++c)
        #pragma unroll
        for (int nf = 0; nf < 4; ++nf)
          acc[mf][nf] = __builtin_amdgcn_mfma_f32_16x16x32_f16(av[mf][c], buf[nf*2 + c], acc[mf][nf], 0, 0, 0);
  };

  LDB(bufA, 0);
  LDP(pwA, 0);
  for (int pn = 0; pn < 16; ++pn) {
    const int b = pn*8;
    LDB(bufB, b+1);                                  MSTEP(bufA, pwA, 0, 0);
    LDB(bufA, b+2);                                  MSTEP(bufB, pwA, 1, 0);
    LDB(bufB, b+3); LDP(pwB, pn*2+1);                MSTEP(bufA, pwA, 2, 1);
    LDB(bufA, b+4);                                  MSTEP(bufB, pwA, 3, 1);
    LDB(bufB, b+5);                                  MSTEP(bufA, pwB, 0, 0);
    LDB(bufA, b+6);                                  MSTEP(bufB, pwB, 1, 0);
    LDB(bufB, b+7); LDP(pwA, (pn < 15) ? pn*2+2 : 31); MSTEP(bufA, pwB, 2, 1);
    LDB(bufA, (pn < 15) ? b+8 : 127);                MSTEP(bufB, pwB, 3, 1);
  }
  asm volatile("s_waitcnt vmcnt(0)" ::: "memory");

  #pragma unroll
  for (int mf = 0; mf < 4; ++mf)
    #pragma unroll
    for (int nf = 0; nf < 4; ++nf) {
      int col = wx*64 + nf*16 + l15;
      #pragma unroll
      for (int r = 0; r < 4; ++r) {
        int row = wy*64 + mf*16 + quad*4 + r;
        out[obase + (size_t)row*opitch + col] = (_Float16)acc[mf][nf][r];
      }
    }
}

// ---------------------------------------------------------------------------
// kreduce: sum fp16 K-partials, apply inv_tp, silu/sigmoid gates, emit s,v.
// ---------------------------------------------------------------------------
__global__ __launch_bounds__(256) void kreduce(char* __restrict__ ws)
{
  const int id = blockIdx.x*256 + threadIdx.x;   // < 4096*128
  const int n = id >> 7, w = id & 127;
  const _Float16* pz0 = (const _Float16*)(ws + OFF_PZ0);
  const _Float16* pz1 = (const _Float16*)(ws + OFF_PZ1);
  _Float16* sf = (_Float16*)(ws + OFF_SF);
  _Float16* vf = (_Float16*)(ws + OFF_VF);
  const size_t b = (size_t)n*256;
  float zs = ((float)pz0[b + w] + (float)pz0[1048576 + b + w]
            + (float)pz0[2097152 + b + w] + (float)pz0[3145728 + b + w]) * INV_TP;
  float zg = ((float)pz0[b + 128 + w] + (float)pz0[1048576 + b + 128 + w]
            + (float)pz0[2097152 + b + 128 + w] + (float)pz0[3145728 + b + 128 + w]) * INV_TP;
  float s = zs / (1.f + __expf(-zs));
  float g = 1.f / (1.f + __expf(-zg));
  sf[id] = (_Float16)s;
  #pragma unroll
  for (int i = 0; i < 3; ++i) {
    size_t r = ((size_t)i*4096 + (size_t)n)*128 + w;
    float z1v = ((float)pz1[r] + (float)pz1[1572864 + r]) * INV_TP;
    vf[(size_t)i*524288 + (size_t)n*128 + w] = (_Float16)(z1v * g);
  }
}

// ---------------------------------------------------------------------------
// kscstats: species-gathered skip terms, y0/y1 += inv_sc * h @ Wsc[:,sp,:],
// fused with the per-group stat accumulation.
// ---------------------------------------------------------------------------
__global__ __launch_bounds__(256) void kscstats(char* __restrict__ ws,
    const float* __restrict__ nfh,
    const float* __restrict__ Wsc0, const float* __restrict__ Wsc1,
    const int* __restrict__ batch)
{
  const int t = threadIdx.x;
  const int node = blockIdx.x*2 + (t >> 7);
  const int w = t & 127;
  const int sp = ((const int*)(ws + OFF_SP))[node];
  const float* h = nfh + (size_t)node*512;
  float a0 = 0.f, a10 = 0.f, a11 = 0.f, a12 = 0.f;
  for (int u = 0; u < 128; ++u) {
    const size_t wi = (size_t)(u*10 + sp)*128 + w;
    float w0 = Wsc0[wi];
    float w1 = Wsc1[wi];
    a0 += h[u] * w0;
    a10 += h[128 + u*3 + 0] * w1;
    a11 += h[128 + u*3 + 1] * w1;
    a12 += h[128 + u*3 + 2] * w1;
  }
  float* y0 = (float*)(ws + OFF_Y0);
  float* y1 = (float*)(ws + OFF_Y1);
  const size_t i0 = (size_t)node*128 + w;
  float y0n  = y0[i0]           + INV_SC * a0;
  float y1n0 = y1[i0]           + INV_SC * a10;
  float y1n1 = y1[524288 + i0]  + INV_SC * a11;
  float y1n2 = y1[1048576 + i0] + INV_SC * a12;
  y0[i0] = y0n;
  y1[i0] = y1n0;
  y1[524288 + i0]  = y1n1;
  y1[1048576 + i0] = y1n2;

  float s0 = y0n, ss0 = y0n*y0n, ss1 = y1n0*y1n0 + y1n1*y1n1 + y1n2*y1n2;
  #pragma unroll
  for (int m = 1; m < 64; m <<= 1) {
    s0  += __shfl_xor(s0, m, 64);
    ss0 += __shfl_xor(ss0, m, 64);
    ss1 += __shfl_xor(ss1, m, 64);
  }
  __shared__ float red[4][3];
  if ((t & 63) == 0) {
    red[t >> 6][0] = s0; red[t >> 6][1] = ss0; red[t >> 6][2] = ss1;
  }
  __syncthreads();
  if ((t & 127) == 0) {
    const int wv = t >> 6;             // 0 (node A) or 2 (node B)
    float* stp = (float*)(ws + OFF_ST);
    const int g = batch[node];
    atomicAdd(&stp[g],       red[wv][0] + red[wv+1][0]);
    atomicAdd(&stp[64 + g],  red[wv][1] + red[wv+1][1]);
    atomicAdd(&stp[128 + g], red[wv][2] + red[wv+1][2]);
    atomicAdd(&stp[192 + g], 1.f);
  }
}

// ---------------------------------------------------------------------------
// kfinal: group-norm + residual add + interleave into output layout.
// ---------------------------------------------------------------------------
__global__ __launch_bounds__(256) void kfinal(char* __restrict__ ws, const int* __restrict__ batch,
    const float* __restrict__ lnw0, const float* __restrict__ lnb0, const float* __restrict__ lnw1,
    float* __restrict__ outp)
{
  const int id = blockIdx.x*256 + threadIdx.x;   // < 4096*512
  const int n = id >> 9, c = id & 511;
  const float* st = (const float*)(ws + OFF_ST);
  const int g = batch[n];
  const float cnt = fmaxf(st[192 + g], 1.f);
  float val;
  if (c < 128) {
    const float* y0 = (const float*)(ws + OFF_Y0);
    const float* o0 = (const float*)(ws + OFF_O0);
    float m0   = st[g] / (cnt * 128.f);
    float var0 = st[64 + g] / (cnt * 128.f) - m0*m0;
    float inv0 = 1.f / (sqrtf(fmaxf(var0, 0.f)) + LN_EPS);
    val = (y0[(size_t)n*128 + c] - m0) * inv0 * lnw0[c] + lnb0[c] + o0[(size_t)n*128 + c];
  } else {
    int cc = c - 128, w = cc / 3, i = cc - w*3;
    const float* y1 = (const float*)(ws + OFF_Y1);
    const float* o1 = (const float*)(ws + OFF_O1);
    float inv1 = 1.f / (sqrtf(fmaxf(st[128 + g] / (cnt * 384.f), 0.f)) + LN_EPS);
    val = y1[(size_t)i*524288 + (size_t)n*128 + w] * inv1 * lnw1[w]
        + o1[(size_t)i*524288 + (size_t)n*128 + w];
  }
  outp[id] = val;
}

// ---------------------------------------------------------------------------
extern "C" void kernel_launch(void* const* d_in, const int* in_sizes, int n_in,
                              void* d_out, int out_size, void* d_ws, size_t ws_size,
                              hipStream_t stream)
{
  const float* nfh   = (const float*)d_in[0];
  const float* nfu   = (const float*)d_in[1];
  const float* oneh  = (const float*)d_in[2];
  const int*   batch = (const int*)d_in[3];
  const float* Wh0   = (const float*)d_in[4];
  const float* Wh1   = (const float*)d_in[5];
  const float* Wu0   = (const float*)d_in[6];
  const float* Wu1   = (const float*)d_in[7];
  const float* Wt00  = (const float*)d_in[8];
  const float* Wt11  = (const float*)d_in[9];
  const float* Wt01  = (const float*)d_in[10];
  const float* Wt10  = (const float*)d_in[11];
  const float* Wp0   = (const float*)d_in[12];
  const float* bp0   = (const float*)d_in[13];
  const float* Wp1   = (const float*)d_in[14];
  const float* Wsc0  = (const float*)d_in[15];
  const float* Wsc1  = (const float*)d_in[16];
  const float* lnw0  = (const float*)d_in[17];
  const float* lnb0  = (const float*)d_in[18];
  const float* lnw1  = (const float*)d_in[19];
  const float* Ws0   = (const float*)d_in[20];
  const float* bs0   = (const float*)d_in[21];
  const float* Ws1   = (const float*)d_in[22];
  char* ws = (char*)d_ws;

  if (ws_size < WS_NEED) {
    // Signal: workspace too small (distinct failure signature, no OOB writes)
    hipMemsetAsync(d_out, 0, (size_t)out_size * sizeof(float), stream);
    return;
  }

  kconv<<<1560, 256, 0, stream>>>(nfh, nfu, oneh, Wt00, Wt11, Wt01, Wt10,
                                  Wh0, Wh1, Wu0, Wu1, Wp0, Wp1, Ws0, Ws1, ws);
  kprep<<<256, 256, 0, stream>>>(ws);
  kbig<<<448, 256, 0, stream>>>(ws);
  kreduce<<<2048, 256, 0, stream>>>(ws);
  ktail<<<256, 256, 0, stream>>>(ws, bp0, bs0);
  kscstats<<<2048, 256, 0, stream>>>(ws, nfh, Wsc0, Wsc1, batch);
  kfinal<<<8192, 256, 0, stream>>>(ws, batch, lnw0, lnb0, lnw1, (float*)d_out);
}